// Round 1
// baseline (106.027 us; speedup 1.0000x reference)
//
#include <hip/hip_runtime.h>

#define NUM_WIRES 4
#define NUM_LAYERS 2

// One thread simulates one batch element's 16-amplitude state entirely in
// registers. Gate matrices (shared across the whole batch) are computed once
// per block into LDS by threads 0..7.
//
// State layout: amp[i], i = b0*8 + b1*4 + b2*2 + b3 (wire w has bit mask 8>>w),
// matching the reference's (B,2,2,2,2) axis order.

template <int M>
__device__ __forceinline__ void apply_1q(float sr[16], float si[16], const float* __restrict__ G) {
    // G = {u00r,u00i, u01r,u01i, u10r,u10i, u11r,u11i}; new[j] = U[j][0]*s0 + U[j][1]*s1
    const float u00r = G[0], u00i = G[1], u01r = G[2], u01i = G[3];
    const float u10r = G[4], u10i = G[5], u11r = G[6], u11i = G[7];
#pragma unroll
    for (int i = 0; i < 16; ++i) {
        if (!(i & M)) {
            const int j = i | M;
            const float ar = sr[i], ai = si[i];
            const float br = sr[j], bi = si[j];
            sr[i] = u00r * ar - u00i * ai + u01r * br - u01i * bi;
            si[i] = u00r * ai + u00i * ar + u01r * bi + u01i * br;
            sr[j] = u10r * ar - u10i * ai + u11r * br - u11i * bi;
            si[j] = u10r * ai + u10i * ar + u11r * bi + u11i * br;
        }
    }
}

template <int CM, int TM>
__device__ __forceinline__ void cnot(float sr[16], float si[16]) {
    // where control bit set, flip target bit: pure register permutation
#pragma unroll
    for (int i = 0; i < 16; ++i) {
        if ((i & CM) && !(i & TM)) {
            const int j = i | TM;
            float t;
            t = sr[i]; sr[i] = sr[j]; sr[j] = t;
            t = si[i]; si[i] = si[j]; si[j] = t;
        }
    }
}

__global__ __launch_bounds__(256) void qsim_kernel(const float* __restrict__ x,
                                                   const float* __restrict__ params,
                                                   float* __restrict__ out, int batch) {
    __shared__ float g[NUM_LAYERS][NUM_WIRES][8];

    const int tid = threadIdx.x;
    if (tid < NUM_LAYERS * NUM_WIRES) {
        const int layer = tid >> 2, wire = tid & 3;
        const float p0 = params[(layer * NUM_WIRES + wire) * 2 + 0];  // RZ angle
        const float p1 = params[(layer * NUM_WIRES + wire) * 2 + 1];  // RX angle
        float cz, sz, cx, sx;
        __sincosf(0.5f * p0, &sz, &cz);
        __sincosf(0.5f * p1, &sx, &cx);
        // U = RX(p1) @ RZ(p0); e = e^{-i p0/2} = (cz, -sz)
        float* G = g[layer][wire];
        G[0] = cx * cz;   G[1] = -cx * sz;   // U00 = cx * e
        G[2] = sx * sz;   G[3] = -sx * cz;   // U01 = -i*sx * conj(e)
        G[4] = -sx * sz;  G[5] = -sx * cz;   // U10 = -i*sx * e
        G[6] = cx * cz;   G[7] = cx * sz;    // U11 = cx * conj(e)
    }
    __syncthreads();

    const int b = blockIdx.x * 256 + tid;
    if (b >= batch) return;

    const float4 xv = reinterpret_cast<const float4*>(x)[b];
    float c0, s0, c1, s1, c2, s2, c3, s3;
    __sincosf(0.5f * xv.x, &s0, &c0);
    __sincosf(0.5f * xv.y, &s1, &c1);
    __sincosf(0.5f * xv.z, &s2, &c2);
    __sincosf(0.5f * xv.w, &s3, &c3);

    float sr[16], si[16];
#pragma unroll
    for (int i = 0; i < 16; ++i) {
        const float a0 = (i & 8) ? s0 : c0;
        const float a1 = (i & 4) ? s1 : c1;
        const float a2 = (i & 2) ? s2 : c2;
        const float a3 = (i & 1) ? s3 : c3;
        sr[i] = a0 * a1 * a2 * a3;
        si[i] = 0.0f;  // constant-folds through layer-0 gate math
    }

#pragma unroll
    for (int layer = 0; layer < NUM_LAYERS; ++layer) {
        apply_1q<8>(sr, si, g[layer][0]);
        apply_1q<4>(sr, si, g[layer][1]);
        apply_1q<2>(sr, si, g[layer][2]);
        apply_1q<1>(sr, si, g[layer][3]);
        cnot<8, 4>(sr, si);  // CNOT(0,1)
        cnot<4, 2>(sr, si);  // CNOT(1,2)
        cnot<2, 1>(sr, si);  // CNOT(2,3)
        cnot<1, 8>(sr, si);  // CNOT(3,0)
    }

    float p[16];
#pragma unroll
    for (int i = 0; i < 16; ++i) p[i] = sr[i] * sr[i] + si[i] * si[i];

    float e0 = 0.f, e1 = 0.f, e2 = 0.f, e3 = 0.f;
#pragma unroll
    for (int i = 0; i < 16; ++i) {
        e0 += (i & 8) ? -p[i] : p[i];
        e1 += (i & 4) ? -p[i] : p[i];
        e2 += (i & 2) ? -p[i] : p[i];
        e3 += (i & 1) ? -p[i] : p[i];
    }

    reinterpret_cast<float4*>(out)[b] = make_float4(e0, e1, e2, e3);
}

extern "C" void kernel_launch(void* const* d_in, const int* in_sizes, int n_in,
                              void* d_out, int out_size, void* d_ws, size_t ws_size,
                              hipStream_t stream) {
    const float* x = (const float*)d_in[0];        // (B, 4) float32
    const float* params = (const float*)d_in[1];   // (2, 4, 2) float32
    float* out = (float*)d_out;                    // (B, 4) float32
    const int batch = in_sizes[0] / NUM_WIRES;
    const int blocks = (batch + 255) / 256;
    qsim_kernel<<<blocks, 256, 0, stream>>>(x, params, out, batch);
}

// Round 2
// 81.488 us; speedup vs baseline: 1.3011x; 1.3011x over previous
//
#include <hip/hip_runtime.h>

#define NUM_WIRES 4
#define NUM_LAYERS 2

// Strategy:
//  - Prelude kernel (1 small block) computes the 8 fused RZ->RX 2x2 unitaries
//    from params into d_ws (64 floats). Main kernel reads them via uniform
//    constant-offset loads -> s_load -> SGPRs -> free scalar operands in FMAs.
//  - Layer-0 gates commute with the initial product state: apply them to the
//    per-wire complex 2-vectors (8 inst/wire) then form the 16-amp complex
//    outer product, instead of 4 full-state gate applications.
//  - CNOTs are compile-time register permutations (free).
//  - All complex arithmetic in explicit fmaf chains.
//
// State layout: amp[i], i bit3=wire0, bit2=wire1, bit1=wire2, bit0=wire3,
// matching the reference's (B,2,2,2,2) axis order.

__global__ void gate_prep(const float* __restrict__ params, float* __restrict__ g) {
    const int t = threadIdx.x;
    if (t < NUM_LAYERS * NUM_WIRES) {
        const float p0 = params[t * 2 + 0];  // RZ angle
        const float p1 = params[t * 2 + 1];  // RX angle
        float cz, sz, cx, sx;
        __sincosf(0.5f * p0, &sz, &cz);
        __sincosf(0.5f * p1, &sx, &cx);
        // U = RX(p1) @ RZ(p0); e = e^{-i p0/2} = (cz, -sz)
        float* G = g + t * 8;
        G[0] = cx * cz;   G[1] = -cx * sz;   // u00
        G[2] = sx * sz;   G[3] = -sx * cz;   // u01
        G[4] = -sx * sz;  G[5] = -sx * cz;   // u10
        G[6] = cx * cz;   G[7] = cx * sz;    // u11
    }
}

// out = U @ (c, s) with (c,s) real: 8 FMAs
__device__ __forceinline__ void gate_factor(float c, float s, const float* __restrict__ G,
                                            float& v0r, float& v0i, float& v1r, float& v1i) {
    v0r = fmaf(G[0], c, G[2] * s);
    v0i = fmaf(G[1], c, G[3] * s);
    v1r = fmaf(G[4], c, G[6] * s);
    v1i = fmaf(G[5], c, G[7] * s);
}

__device__ __forceinline__ void cmul(float ar, float ai, float br, float bi,
                                     float& orr, float& oi) {
    orr = fmaf(ar, br, -ai * bi);
    oi  = fmaf(ar, bi,  ai * br);
}

template <int M>
__device__ __forceinline__ void apply_1q(float sr[16], float si[16], const float* __restrict__ G) {
    const float u00r = G[0], u00i = G[1], u01r = G[2], u01i = G[3];
    const float u10r = G[4], u10i = G[5], u11r = G[6], u11i = G[7];
#pragma unroll
    for (int i = 0; i < 16; ++i) {
        if (!(i & M)) {
            const int j = i | M;
            const float ar = sr[i], ai = si[i];
            const float br = sr[j], bi = si[j];
            sr[i] = fmaf(u00r, ar, fmaf(-u00i, ai, fmaf(u01r, br, -u01i * bi)));
            si[i] = fmaf(u00i, ar, fmaf(u00r, ai, fmaf(u01i, br, u01r * bi)));
            sr[j] = fmaf(u10r, ar, fmaf(-u10i, ai, fmaf(u11r, br, -u11i * bi)));
            si[j] = fmaf(u10i, ar, fmaf(u10r, ai, fmaf(u11i, br, u11r * bi)));
        }
    }
}

template <int CM, int TM>
__device__ __forceinline__ void cnot(float sr[16], float si[16]) {
#pragma unroll
    for (int i = 0; i < 16; ++i) {
        if ((i & CM) && !(i & TM)) {
            const int j = i | TM;
            float t;
            t = sr[i]; sr[i] = sr[j]; sr[j] = t;
            t = si[i]; si[i] = si[j]; si[j] = t;
        }
    }
}

__global__ __launch_bounds__(256) void qsim_kernel(const float* __restrict__ x,
                                                   const float* __restrict__ g,
                                                   float* __restrict__ out, int batch) {
    const int b = blockIdx.x * 256 + threadIdx.x;
    if (b >= batch) return;

    const float4 xv = reinterpret_cast<const float4*>(x)[b];

    // Per-wire RY(x)|0> = (c, s), then layer-0 gate on the 2-vector factor.
    float w0r[2], w0i[2], w1r[2], w1i[2], w2r[2], w2i[2], w3r[2], w3i[2];
    {
        float c, s;
        __sincosf(0.5f * xv.x, &s, &c);
        gate_factor(c, s, g + 0,  w0r[0], w0i[0], w0r[1], w0i[1]);
        __sincosf(0.5f * xv.y, &s, &c);
        gate_factor(c, s, g + 8,  w1r[0], w1i[0], w1r[1], w1i[1]);
        __sincosf(0.5f * xv.z, &s, &c);
        gate_factor(c, s, g + 16, w2r[0], w2i[0], w2r[1], w2i[1]);
        __sincosf(0.5f * xv.w, &s, &c);
        gate_factor(c, s, g + 24, w3r[0], w3i[0], w3r[1], w3i[1]);
    }

    // Complex outer product: m = w0 (x) w1, n = w2 (x) w3, state = m (x) n.
    float mr[4], mi[4], nr[4], ni[4];
#pragma unroll
    for (int p = 0; p < 2; ++p)
#pragma unroll
        for (int q = 0; q < 2; ++q) {
            cmul(w0r[p], w0i[p], w1r[q], w1i[q], mr[p * 2 + q], mi[p * 2 + q]);
            cmul(w2r[p], w2i[p], w3r[q], w3i[q], nr[p * 2 + q], ni[p * 2 + q]);
        }

    float sr[16], si[16];
#pragma unroll
    for (int i = 0; i < 16; ++i)
        cmul(mr[i >> 2], mi[i >> 2], nr[i & 3], ni[i & 3], sr[i], si[i]);

    // Layer 0 CNOT ring
    cnot<8, 4>(sr, si);
    cnot<4, 2>(sr, si);
    cnot<2, 1>(sr, si);
    cnot<1, 8>(sr, si);

    // Layer 1: full-state gates + CNOT ring
    apply_1q<8>(sr, si, g + 32);
    apply_1q<4>(sr, si, g + 40);
    apply_1q<2>(sr, si, g + 48);
    apply_1q<1>(sr, si, g + 56);
    cnot<8, 4>(sr, si);
    cnot<4, 2>(sr, si);
    cnot<2, 1>(sr, si);
    cnot<1, 8>(sr, si);

    // Probabilities and <Z_w> via pairwise sum/difference tree.
    float p[16];
#pragma unroll
    for (int i = 0; i < 16; ++i) p[i] = fmaf(sr[i], sr[i], si[i] * si[i]);

    float d0[8], s1[8];
#pragma unroll
    for (int k = 0; k < 8; ++k) { d0[k] = p[2 * k] - p[2 * k + 1]; s1[k] = p[2 * k] + p[2 * k + 1]; }
    const float e3 = ((d0[0] + d0[1]) + (d0[2] + d0[3])) + ((d0[4] + d0[5]) + (d0[6] + d0[7]));
    const float e2 = ((s1[0] - s1[1]) + (s1[2] - s1[3])) + ((s1[4] - s1[5]) + (s1[6] - s1[7]));
    float s2[4];
#pragma unroll
    for (int k = 0; k < 4; ++k) s2[k] = s1[2 * k] + s1[2 * k + 1];
    const float e1 = (s2[0] - s2[1]) + (s2[2] - s2[3]);
    const float e0 = (s2[0] + s2[1]) - (s2[2] + s2[3]);

    reinterpret_cast<float4*>(out)[b] = make_float4(e0, e1, e2, e3);
}

extern "C" void kernel_launch(void* const* d_in, const int* in_sizes, int n_in,
                              void* d_out, int out_size, void* d_ws, size_t ws_size,
                              hipStream_t stream) {
    const float* x = (const float*)d_in[0];        // (B, 4) float32
    const float* params = (const float*)d_in[1];   // (2, 4, 2) float32
    float* out = (float*)d_out;                    // (B, 4) float32
    float* g = (float*)d_ws;                       // 64 floats of gate matrices
    const int batch = in_sizes[0] / NUM_WIRES;

    gate_prep<<<1, 64, 0, stream>>>(params, g);
    const int blocks = (batch + 255) / 256;
    qsim_kernel<<<blocks, 256, 0, stream>>>(x, g, out, batch);
}

// Round 3
// 80.825 us; speedup vs baseline: 1.3118x; 1.0082x over previous
//
#include <hip/hip_runtime.h>

#define NUM_WIRES 4
#define NUM_LAYERS 2

typedef float v2 __attribute__((ext_vector_type(2)));

// Complex amplitudes stored as v2 (re, im); arithmetic expressed as 2-wide
// packed ops so the backend emits v_pk_fma_f32 (2x scalar f32 rate on CDNA),
// with op_sel/neg modifiers absorbing the (re,im) swaps and sign flips.
//
// ws layout (floats):
//  [ 0..31]  layer-0 fused U=RX*RZ per wire: {u00r,u00i,u01r,u01i,u10r,u10i,u11r,u11i}
//  [32..39]  layer-1 RX per wire: {cos, sin}
//  [40..71]  layer-1 combined RZ diagonal (all 4 wires folded): 16 x {dr, di}
//
// State layout: amp[i], bit3=wire0 ... bit0=wire3 (reference (B,2,2,2,2) order).

__global__ void gate_prep(const float* __restrict__ params, float* __restrict__ g) {
    const int t = threadIdx.x;
    if (t < 4) {
        // layer-0 fused U per wire
        const float p0 = params[t * 2 + 0];  // RZ
        const float p1 = params[t * 2 + 1];  // RX
        float cz, sz, cx, sx;
        __sincosf(0.5f * p0, &sz, &cz);
        __sincosf(0.5f * p1, &sx, &cx);
        float* G = g + t * 8;
        G[0] = cx * cz;   G[1] = -cx * sz;   // u00 = cx * e,        e = (cz,-sz)
        G[2] = sx * sz;   G[3] = -sx * cz;   // u01 = -i*sx*conj(e)
        G[4] = -sx * sz;  G[5] = -sx * cz;   // u10 = -i*sx*e
        G[6] = cx * cz;   G[7] = cx * sz;    // u11 = cx * conj(e)
    } else if (t < 8) {
        // layer-1 RX (c,s)
        const int w = t - 4;
        const float p1 = params[(NUM_WIRES + w) * 2 + 1];
        float cx, sx;
        __sincosf(0.5f * p1, &sx, &cx);
        g[32 + w * 2] = cx;
        g[33 + w * 2] = sx;
    } else if (t >= 16 && t < 32) {
        // layer-1 combined RZ diagonal entry i
        const int i = t - 16;
        float dr = 1.f, di = 0.f;
        for (int w = 0; w < NUM_WIRES; ++w) {
            const float p0 = params[(NUM_WIRES + w) * 2 + 0];
            float c, s;
            __sincosf(0.5f * p0, &s, &c);
            // bit==0 -> e^{-ip/2}=(c,-s); bit==1 -> (c,+s). wire w is bit (3-w).
            const float sg = ((i >> (3 - w)) & 1) ? s : -s;
            const float ndr = dr * c - di * sg;
            const float ndi = dr * sg + di * c;
            dr = ndr; di = ndi;
        }
        g[40 + i * 2] = dr;
        g[41 + i * 2] = di;
    }
}

__device__ __forceinline__ v2 mk(float a, float b) { v2 r; r.x = a; r.y = b; return r; }

// complex multiply: 2 packed ops
__device__ __forceinline__ v2 cmul(v2 a, v2 b) {
    const v2 t = mk(-a.y, a.y) * mk(b.y, b.x);
    return __builtin_elementwise_fma(mk(a.x, a.x), b, t);
}

template <int CM, int TM>
__device__ __forceinline__ void cnot(v2 z[16]) {
#pragma unroll
    for (int i = 0; i < 16; ++i) {
        if ((i & CM) && !(i & TM)) {
            const int j = i | TM;
            const v2 t = z[i]; z[i] = z[j]; z[j] = t;
        }
    }
}

__global__ __launch_bounds__(256) void qsim_kernel(const float* __restrict__ x,
                                                   const float* __restrict__ gf,
                                                   float* __restrict__ out, int batch) {
    const int b = blockIdx.x * 256 + threadIdx.x;
    if (b >= batch) return;
    const v2* __restrict__ g = (const v2*)gf;  // uniform constant loads -> SGPRs

    const float4 xv = reinterpret_cast<const float4*>(x)[b];

    // Layer-0: apply the fused gate to each wire's RY(x)|0> = (c,s) factor.
    v2 f[4][2];
    {
        const float xs0 = xv.x, xs1 = xv.y, xs2 = xv.z, xs3 = xv.w;
        float c, s;
        __sincosf(0.5f * xs0, &s, &c);
        f[0][0] = __builtin_elementwise_fma(mk(c, c), g[0], mk(s, s) * g[1]);
        f[0][1] = __builtin_elementwise_fma(mk(c, c), g[2], mk(s, s) * g[3]);
        __sincosf(0.5f * xs1, &s, &c);
        f[1][0] = __builtin_elementwise_fma(mk(c, c), g[4], mk(s, s) * g[5]);
        f[1][1] = __builtin_elementwise_fma(mk(c, c), g[6], mk(s, s) * g[7]);
        __sincosf(0.5f * xs2, &s, &c);
        f[2][0] = __builtin_elementwise_fma(mk(c, c), g[8], mk(s, s) * g[9]);
        f[2][1] = __builtin_elementwise_fma(mk(c, c), g[10], mk(s, s) * g[11]);
        __sincosf(0.5f * xs3, &s, &c);
        f[3][0] = __builtin_elementwise_fma(mk(c, c), g[12], mk(s, s) * g[13]);
        f[3][1] = __builtin_elementwise_fma(mk(c, c), g[14], mk(s, s) * g[15]);
    }

    // Complex outer product: state = (f0 (x) f1) (x) (f2 (x) f3)
    v2 m[4], n[4];
#pragma unroll
    for (int p = 0; p < 2; ++p)
#pragma unroll
        for (int q = 0; q < 2; ++q) {
            m[p * 2 + q] = cmul(f[0][p], f[1][q]);
            n[p * 2 + q] = cmul(f[2][p], f[3][q]);
        }
    v2 z[16];
#pragma unroll
    for (int i = 0; i < 16; ++i) z[i] = cmul(m[i >> 2], n[i & 3]);

    // Layer-0 CNOT ring (register renaming, free)
    cnot<8, 4>(z);
    cnot<4, 2>(z);
    cnot<2, 1>(z);
    cnot<1, 8>(z);

    // Layer-1 RZs: one combined batch-uniform diagonal (v2 index 20+i)
#pragma unroll
    for (int i = 0; i < 16; ++i) z[i] = cmul(g[20 + i], z[i]);

    // Layer-1 RXs: entries {real c, imag -s}; 2 packed ops per amplitude
#pragma unroll
    for (int w = 0; w < 4; ++w) {
        const v2 cs = g[16 + w];
        const float c = cs.x, s = cs.y;
        const int M = 8 >> w;
#pragma unroll
        for (int i = 0; i < 16; ++i) {
            if (!(i & M)) {
                const int j = i | M;
                const v2 a = z[i], bb = z[j];
                // new_a = c*a - i*s*b = (c*ar + s*bi, c*ai - s*br)
                z[i] = __builtin_elementwise_fma(mk(c, c), a,  mk(s, -s) * mk(bb.y, bb.x));
                z[j] = __builtin_elementwise_fma(mk(c, c), bb, mk(s, -s) * mk(a.y, a.x));
            }
        }
    }

    // Layer-1 CNOT ring
    cnot<8, 4>(z);
    cnot<4, 2>(z);
    cnot<2, 1>(z);
    cnot<1, 8>(z);

    // Probabilities and <Z_w> via sum/difference tree
    float p[16];
#pragma unroll
    for (int i = 0; i < 16; ++i) p[i] = fmaf(z[i].x, z[i].x, z[i].y * z[i].y);

    float d0[8], s1[8];
#pragma unroll
    for (int k = 0; k < 8; ++k) {
        d0[k] = p[2 * k] - p[2 * k + 1];
        s1[k] = p[2 * k] + p[2 * k + 1];
    }
    const float e3 = ((d0[0] + d0[1]) + (d0[2] + d0[3])) + ((d0[4] + d0[5]) + (d0[6] + d0[7]));
    const float e2 = ((s1[0] - s1[1]) + (s1[2] - s1[3])) + ((s1[4] - s1[5]) + (s1[6] - s1[7]));
    float s2[4];
#pragma unroll
    for (int k = 0; k < 4; ++k) s2[k] = s1[2 * k] + s1[2 * k + 1];
    const float e1 = (s2[0] - s2[1]) + (s2[2] - s2[3]);
    const float e0 = (s2[0] + s2[1]) - (s2[2] + s2[3]);

    reinterpret_cast<float4*>(out)[b] = make_float4(e0, e1, e2, e3);
}

extern "C" void kernel_launch(void* const* d_in, const int* in_sizes, int n_in,
                              void* d_out, int out_size, void* d_ws, size_t ws_size,
                              hipStream_t stream) {
    const float* x = (const float*)d_in[0];        // (B, 4) float32
    const float* params = (const float*)d_in[1];   // (2, 4, 2) float32
    float* out = (float*)d_out;                    // (B, 4) float32
    float* g = (float*)d_ws;                       // 72 floats of gate constants
    const int batch = in_sizes[0] / NUM_WIRES;

    gate_prep<<<1, 64, 0, stream>>>(params, g);
    const int blocks = (batch + 255) / 256;
    qsim_kernel<<<blocks, 256, 0, stream>>>(x, g, out, batch);
}

// Round 4
// 78.491 us; speedup vs baseline: 1.3508x; 1.0297x over previous
//
#include <hip/hip_runtime.h>

#define NUM_WIRES 4
#define NUM_LAYERS 2

// All-scalar implementation; every batch-uniform gate coefficient is forced
// into SGPRs via readfirstlane so the 16-amp state math runs with minimal
// VGPR pressure (state = 32 VGPRs) and SGPR-operand FMAs.
//
// ws layout (floats):
//  [ 0..15]  layer-0 per wire w: {A=cx*cz, B=cx*sz, C=sx*sz, D=sx*cz}
//  [16..23]  layer-1 RX per wire: {cos, sin}
//  [24..55]  layer-1 combined RZ diagonal (CNOT-ring-conjugated order): 16 x {dr, di}
//
// State layout: amp[i], bit3=wire0 ... bit0=wire3 (reference (B,2,2,2,2) order).

__global__ void gate_prep(const float* __restrict__ params, float* __restrict__ g) {
    const int t = threadIdx.x;
    if (t < 4) {
        // layer-0: products of the fused U = RX * RZ entries
        const float p0 = params[t * 2 + 0];  // RZ
        const float p1 = params[t * 2 + 1];  // RX
        float cz, sz, cx, sx;
        __sincosf(0.5f * p0, &sz, &cz);
        __sincosf(0.5f * p1, &sx, &cx);
        g[t * 4 + 0] = cx * cz;
        g[t * 4 + 1] = cx * sz;
        g[t * 4 + 2] = sx * sz;
        g[t * 4 + 3] = sx * cz;
    } else if (t < 8) {
        // layer-1 RX (c,s)
        const int w = t - 4;
        const float p1 = params[(NUM_WIRES + w) * 2 + 1];
        float cx, sx;
        __sincosf(0.5f * p1, &sx, &cx);
        g[16 + w * 2] = cx;
        g[17 + w * 2] = sx;
    } else if (t >= 16 && t < 32) {
        // layer-1 combined RZ diagonal entry i
        const int i = t - 16;
        float dr = 1.f, di = 0.f;
        for (int w = 0; w < NUM_WIRES; ++w) {
            const float p0 = params[(NUM_WIRES + w) * 2 + 0];
            float c, s;
            __sincosf(0.5f * p0, &s, &c);
            // bit==0 -> e^{-ip/2}=(c,-s); bit==1 -> (c,+s). wire w is bit (3-w).
            const float sg = ((i >> (3 - w)) & 1) ? s : -s;
            const float ndr = dr * c - di * sg;
            const float ndi = dr * sg + di * c;
            dr = ndr; di = ndi;
        }
        g[24 + i * 2] = dr;
        g[25 + i * 2] = di;
    }
}

__device__ __forceinline__ float rfl(float v) {
    return __int_as_float(__builtin_amdgcn_readfirstlane(__float_as_int(v)));
}

// (orr,oi) = (ar,ai) * (br,bi)
__device__ __forceinline__ void cmul(float ar, float ai, float br, float bi,
                                     float& orr, float& oi) {
    orr = fmaf(ar, br, -(ai * bi));
    oi  = fmaf(ar, bi,   ai * br);
}

template <int CM, int TM>
__device__ __forceinline__ void cnot(float zr[16], float zi[16]) {
#pragma unroll
    for (int i = 0; i < 16; ++i) {
        if ((i & CM) && !(i & TM)) {
            const int j = i | TM;
            float t;
            t = zr[i]; zr[i] = zr[j]; zr[j] = t;
            t = zi[i]; zi[i] = zi[j]; zi[j] = t;
        }
    }
}

__global__ __launch_bounds__(256) void qsim_kernel(const float* __restrict__ x,
                                                   const float* __restrict__ gf,
                                                   float* __restrict__ out, int batch) {
    const int b = blockIdx.x * 256 + threadIdx.x;
    if (b >= batch) return;

    // Pull all 56 batch-uniform gate constants into SGPRs.
    float G[56];
#pragma unroll
    for (int k = 0; k < 14; ++k) {
        const float4 v = reinterpret_cast<const float4*>(gf)[k];
        G[4 * k + 0] = rfl(v.x);
        G[4 * k + 1] = rfl(v.y);
        G[4 * k + 2] = rfl(v.z);
        G[4 * k + 3] = rfl(v.w);
    }

    const float4 xv = reinterpret_cast<const float4*>(x)[b];

    // Layer-0: fused gate applied to each wire's RY(x)|0> = (c,s) factor.
    // factor = (v0r + i v0i, v1r + i v1i)
    float fr[4][2], fi[4][2];
    {
        const float xs[4] = {xv.x, xv.y, xv.z, xv.w};
#pragma unroll
        for (int w = 0; w < 4; ++w) {
            float c, s;
            __sincosf(0.5f * xs[w], &s, &c);
            const float A = G[w * 4 + 0], B = G[w * 4 + 1];
            const float C = G[w * 4 + 2], D = G[w * 4 + 3];
            fr[w][0] = fmaf(A, c, C * s);      // u00r*c + u01r*s
            fi[w][0] = fmaf(-B, c, -(D * s));  // u00i*c + u01i*s
            fr[w][1] = fmaf(A, s, -(C * c));   // u10r*c + u11r*s
            fi[w][1] = fmaf(B, s, -(D * c));   // u10i*c + u11i*s
        }
    }

    // Complex outer product: z = (f0 (x) f1) (x) (f2 (x) f3)
    float mr[4], mi[4], nr[4], ni[4];
#pragma unroll
    for (int p = 0; p < 2; ++p)
#pragma unroll
        for (int q = 0; q < 2; ++q) {
            cmul(fr[0][p], fi[0][p], fr[1][q], fi[1][q], mr[p * 2 + q], mi[p * 2 + q]);
            cmul(fr[2][p], fi[2][p], fr[3][q], fi[3][q], nr[p * 2 + q], ni[p * 2 + q]);
        }
    float zr[16], zi[16];
#pragma unroll
    for (int i = 0; i < 16; ++i)
        cmul(mr[i >> 2], mi[i >> 2], nr[i & 3], ni[i & 3], zr[i], zi[i]);

    // Layer-0 CNOT ring (free register permutation)
    cnot<8, 4>(zr, zi);
    cnot<4, 2>(zr, zi);
    cnot<2, 1>(zr, zi);
    cnot<1, 8>(zr, zi);

    // Layer-1 combined RZ diagonal
#pragma unroll
    for (int i = 0; i < 16; ++i) {
        const float dr = G[24 + i * 2], di = G[25 + i * 2];
        const float ar = zr[i], ai = zi[i];
        zr[i] = fmaf(dr, ar, -(di * ai));
        zi[i] = fmaf(dr, ai,   di * ar);
    }

    // Layer-1 RX per wire: new_a = c*a - i*s*b -> (c*ar + s*bi, c*ai - s*br)
#pragma unroll
    for (int w = 0; w < 4; ++w) {
        const float c = G[16 + w * 2], s = G[17 + w * 2];
        const int M = 8 >> w;
#pragma unroll
        for (int i = 0; i < 16; ++i) {
            if (!(i & M)) {
                const int j = i | M;
                const float ar = zr[i], ai = zi[i];
                const float br = zr[j], bi = zi[j];
                zr[i] = fmaf(c, ar,   s * bi);
                zi[i] = fmaf(c, ai, -(s * br));
                zr[j] = fmaf(c, br,   s * ai);
                zi[j] = fmaf(c, bi, -(s * ar));
            }
        }
    }

    // Layer-1 CNOT ring
    cnot<8, 4>(zr, zi);
    cnot<4, 2>(zr, zi);
    cnot<2, 1>(zr, zi);
    cnot<1, 8>(zr, zi);

    // Probabilities and <Z_w> via sum/difference tree
    float p[16];
#pragma unroll
    for (int i = 0; i < 16; ++i) p[i] = fmaf(zr[i], zr[i], zi[i] * zi[i]);

    float d0[8], s1[8];
#pragma unroll
    for (int k = 0; k < 8; ++k) {
        d0[k] = p[2 * k] - p[2 * k + 1];
        s1[k] = p[2 * k] + p[2 * k + 1];
    }
    const float e3 = ((d0[0] + d0[1]) + (d0[2] + d0[3])) + ((d0[4] + d0[5]) + (d0[6] + d0[7]));
    const float e2 = ((s1[0] - s1[1]) + (s1[2] - s1[3])) + ((s1[4] - s1[5]) + (s1[6] - s1[7]));
    float s2[4];
#pragma unroll
    for (int k = 0; k < 4; ++k) s2[k] = s1[2 * k] + s1[2 * k + 1];
    const float e1 = (s2[0] - s2[1]) + (s2[2] - s2[3]);
    const float e0 = (s2[0] + s2[1]) - (s2[2] + s2[3]);

    reinterpret_cast<float4*>(out)[b] = make_float4(e0, e1, e2, e3);
}

extern "C" void kernel_launch(void* const* d_in, const int* in_sizes, int n_in,
                              void* d_out, int out_size, void* d_ws, size_t ws_size,
                              hipStream_t stream) {
    const float* x = (const float*)d_in[0];        // (B, 4) float32
    const float* params = (const float*)d_in[1];   // (2, 4, 2) float32
    float* out = (float*)d_out;                    // (B, 4) float32
    float* g = (float*)d_ws;                       // 56 floats of gate constants
    const int batch = in_sizes[0] / NUM_WIRES;

    gate_prep<<<1, 64, 0, stream>>>(params, g);
    const int blocks = (batch + 255) / 256;
    qsim_kernel<<<blocks, 256, 0, stream>>>(x, g, out, batch);
}